// Round 13
// baseline (114.651 us; speedup 1.0000x reference)
//
#include <hip/hip_runtime.h>
#include <math.h>

#define B_  256
#define H_  256
#define C_  16384
#define S_  64
#define CS_ 32
#define K_  8
#define EPS 1e-8f
#define RET_ ((size_t)B_ * K_ * S_ * H_)   // 33,554,432 f32

typedef __attribute__((ext_vector_type(8))) short short8v;
typedef __attribute__((ext_vector_type(4))) float f32x4;

// ws: candbuf u64[256*2048] (4 MB) @0; mode i32 @4MB.
// d_out: [retrieved 33.5M f32][top_scores 2048 f32]; no scratch in d_out.

__device__ inline unsigned short f2bf(float f) {           // RTNE f32->bf16
    unsigned u = __builtin_bit_cast(unsigned, f);
    unsigned r = u + 0x7fffu + ((u >> 16) & 1u);
    return (unsigned short)(r >> 16);
}
__device__ inline unsigned ordf(float f) {                 // order-preserving f32->u32
    unsigned u = __builtin_bit_cast(unsigned, f);
    return u ^ ((u >> 31) ? 0xFFFFFFFFu : 0x80000000u);
}
__device__ inline short8v pack8(float4 a, float4 b) {
    short8v r;
    r[0] = (short)f2bf(a.x); r[1] = (short)f2bf(a.y);
    r[2] = (short)f2bf(a.z); r[3] = (short)f2bf(a.w);
    r[4] = (short)f2bf(b.x); r[5] = (short)f2bf(b.y);
    r[6] = (short)f2bf(b.z); r[7] = (short)f2bf(b.w);
    return r;
}
__device__ inline void ce(unsigned long long& a, unsigned long long& b) {  // desc
    unsigned long long lo = a < b ? a : b;
    a = a < b ? b : a;
    b = lo;
}
// best: sorted desc. Merge with xor-partner's sorted-desc list -> top-8 of 16.
__device__ inline void merge_shfl(unsigned long long best[8], int xorlane) {
    unsigned long long m[8];
    #pragma unroll
    for (int i = 0; i < 8; ++i) {
        unsigned long long p = __shfl_xor(best[7 - i], xorlane);
        m[i] = best[i] > p ? best[i] : p;      // bitonic first step: top-8 set
    }
    ce(m[0], m[4]); ce(m[1], m[5]); ce(m[2], m[6]); ce(m[3], m[7]);
    ce(m[0], m[2]); ce(m[1], m[3]); ce(m[4], m[6]); ce(m[5], m[7]);
    ce(m[0], m[1]); ce(m[2], m[3]); ce(m[4], m[5]); ce(m[6], m[7]);
    #pragma unroll
    for (int i = 0; i < 8; ++i) best[i] = m[i];
}

// Fused bf16-MFMA sim + per-tile per-row top-8 (all-thread parallel).
// Block = 64b x 64c; K chunked by 32, LDS double-buffered staging (R9).
// Block 1024: detect is_compressed storage width.
#define LSTR 40
__global__ __launch_bounds__(256) void simsel_kernel(const float* __restrict__ q,
                                                     const float* __restrict__ e,
                                                     const unsigned* __restrict__ icw,
                                                     unsigned long long* __restrict__ candbuf,
                                                     int* __restrict__ mode) {
    const int t = threadIdx.x;
    if (blockIdx.x == 1024) {   // byte-bool (1) vs int32 (0)
        __shared__ int f;
        if (t == 0) f = 0;
        __syncthreads();
        int any = 0;
        for (int i = t; i < 4096; i += 256)
            if (icw[i] & 0xFFFFFF00u) any = 1;
        if (any) atomicOr(&f, 1);
        __syncthreads();
        if (t == 0) *mode = f;
        return;
    }

    __shared__ union {
        unsigned short st[4][64 * LSTR];   // [Q0, Q1, E0, E1] 5.1 KB each
        float tile[64 * 65];               // f32 sim tile (16.6 KB)
    } sm;
    __shared__ float einv_s[64];
    const int lane = t & 63, wv = t >> 6;
    const int wm = wv >> 1, wn = wv & 1;
    // XCD swizzle: bids {x, x+8, x+16, x+24} share one c-tile on one XCD.
    const int bid = blockIdx.x;
    const int ct = (bid & 7) * 32 + (bid >> 5);
    const int bt = (bid >> 3) & 3;
    const int c0 = ct * 64, b0 = bt * 64;
    const int r = t >> 2, g = t & 3;              // staging: row, quarter
    const float4* q4 = (const float4*)q;
    const float4* e4 = (const float4*)e;

    float esq = 0.f;
    f32x4 acc[2][2];
    #pragma unroll
    for (int i = 0; i < 2; ++i)
        #pragma unroll
        for (int j = 0; j < 2; ++j) acc[i][j] = (f32x4){0.f, 0.f, 0.f, 0.f};

    // prologue: stage phase 0 into buffers 0
    {
        float4 qa0 = q4[(size_t)(b0 + r) * 64 + g * 2];
        float4 qa1 = q4[(size_t)(b0 + r) * 64 + g * 2 + 1];
        float4 ea0 = e4[(size_t)(c0 + r) * 64 + g * 2];
        float4 ea1 = e4[(size_t)(c0 + r) * 64 + g * 2 + 1];
        esq += ea0.x * ea0.x + ea0.y * ea0.y + ea0.z * ea0.z + ea0.w * ea0.w
             + ea1.x * ea1.x + ea1.y * ea1.y + ea1.z * ea1.z + ea1.w * ea1.w;
        *(short8v*)&sm.st[0][r * LSTR + g * 8] = pack8(qa0, qa1);
        *(short8v*)&sm.st[2][r * LSTR + g * 8] = pack8(ea0, ea1);
    }

    for (int hc = 0; hc < 8; ++hc) {
        const int cur = hc & 1, nxt = cur ^ 1;
        float4 qa0, qa1, ea0, ea1;
        if (hc < 7) {   // issue next-phase loads BEFORE the barrier
            qa0 = q4[(size_t)(b0 + r) * 64 + (hc + 1) * 8 + g * 2];
            qa1 = q4[(size_t)(b0 + r) * 64 + (hc + 1) * 8 + g * 2 + 1];
            ea0 = e4[(size_t)(c0 + r) * 64 + (hc + 1) * 8 + g * 2];
            ea1 = e4[(size_t)(c0 + r) * 64 + (hc + 1) * 8 + g * 2 + 1];
        }
        __syncthreads();   // buf[cur] staged & prior readers of buf[nxt] done

        short8v afr[2], bfr[2];
        #pragma unroll
        for (int mi = 0; mi < 2; ++mi)
            afr[mi] = *(short8v*)&sm.st[cur][(wm * 32 + mi * 16 + (lane & 15)) * LSTR + (lane >> 4) * 8];
        #pragma unroll
        for (int ni = 0; ni < 2; ++ni)
            bfr[ni] = *(short8v*)&sm.st[2 + cur][(wn * 32 + ni * 16 + (lane & 15)) * LSTR + (lane >> 4) * 8];
        #pragma unroll
        for (int mi = 0; mi < 2; ++mi)
            #pragma unroll
            for (int ni = 0; ni < 2; ++ni)
                acc[mi][ni] = __builtin_amdgcn_mfma_f32_16x16x32_bf16(
                    afr[mi], bfr[ni], acc[mi][ni], 0, 0, 0);

        if (hc < 7) {   // stage next phase into the other buffer
            esq += ea0.x * ea0.x + ea0.y * ea0.y + ea0.z * ea0.z + ea0.w * ea0.w
                 + ea1.x * ea1.x + ea1.y * ea1.y + ea1.z * ea1.z + ea1.w * ea1.w;
            *(short8v*)&sm.st[nxt][r * LSTR + g * 8] = pack8(qa0, qa1);
            *(short8v*)&sm.st[2 + nxt][r * LSTR + g * 8] = pack8(ea0, ea1);
        }
    }

    esq += __shfl_xor(esq, 1);
    esq += __shfl_xor(esq, 2);                    // 4-lane group = one e row
    if (g == 0) einv_s[r] = 1.0f / fmaxf(sqrtf(esq), EPS);
    __syncthreads();   // drains final phase's LDS reads; tile may now alias

    // dump scaled sims over the staging region
    #pragma unroll
    for (int mi = 0; mi < 2; ++mi)
        #pragma unroll
        for (int j = 0; j < 4; ++j) {
            int row = wm * 32 + mi * 16 + (lane >> 4) * 4 + j;
            #pragma unroll
            for (int ni = 0; ni < 2; ++ni) {
                int col = wn * 32 + ni * 16 + (lane & 15);
                sm.tile[row * 65 + col] = acc[mi][ni][j] * einv_s[col];
            }
        }
    __syncthreads();

    // thread (r,g): top-8 of its 16 cols, then 2 shfl-merge rounds -> top-8 of 64
    unsigned long long best[8];
    #pragma unroll
    for (int k = 0; k < 8; ++k) best[k] = 0ull;
    for (int i = 0; i < 16; ++i) {
        int c = g * 16 + i;
        float v = sm.tile[r * 65 + c];
        unsigned long long key = ((unsigned long long)ordf(v) << 32)
                               | (unsigned)(0xFFFFFFFFu - (unsigned)(c0 + c));
        if (key > best[7]) {
            best[7] = key;
            #pragma unroll
            for (int k = 7; k > 0; --k)
                if (best[k] > best[k - 1]) {
                    unsigned long long tmp = best[k];
                    best[k] = best[k - 1]; best[k - 1] = tmp;
                }
        }
    }
    merge_shfl(best, 1);   // quarters 0<->1, 2<->3
    merge_shfl(best, 2);   // -> exact per-row top-8 (all 4 threads agree)
    if (g == 0) {
        #pragma unroll
        for (int k = 0; k < 8; ++k)
            candbuf[(size_t)(b0 + r) * 2048 + ct * 8 + k] = best[k];
    }
}

// Grid 2048 = (j,b), bj = j*256 + b (same-b blocks co-XCD: bid%8 == b%8).
// Each block: register pop-merge of row b's 256 sorted 8-lists (cheap to
// duplicate, unlike LDS bitonic) -> parallel bitonic 4-way merge -> exact
// coarse top-32 -> f32 rescore -> keep rank j -> gather its 64KB episode.
__global__ __launch_bounds__(256) void merge_gather_kernel(
        const float* __restrict__ q, const float* __restrict__ e,
        const unsigned long long* __restrict__ candbuf,
        const void* __restrict__ icp, const int* __restrict__ mode,
        const float* __restrict__ epi, const float* __restrict__ comp,
        float* __restrict__ out, float* __restrict__ out_scores) {
    __shared__ unsigned long long wtop[4][32];
    __shared__ unsigned long long m2[2][32];
    __shared__ unsigned long long sel32[32];
    __shared__ float rs[32];
    __shared__ int   ri[32];
    __shared__ int   sel_c;
    const int t = threadIdx.x;
    const int j = blockIdx.x >> 8, b = blockIdx.x & 255;
    const int wv = t >> 6, lane = t & 63;

    // lane's tile list (sorted desc), kept in registers (static select-chain)
    const unsigned long long* lp = candbuf + (size_t)b * 2048 + (size_t)(wv * 64 + lane) * 8;
    unsigned long long k0 = lp[0], k1 = lp[1], k2 = lp[2], k3 = lp[3],
                       k4 = lp[4], k5 = lp[5], k6 = lp[6], k7 = lp[7];
    int p = 0;
    unsigned long long cur = k0;

    for (int it = 0; it < 32; ++it) {          // pop 32: exact wave top-32
        unsigned long long km = cur;
        #pragma unroll
        for (int d = 1; d < 64; d <<= 1) {
            unsigned long long o = __shfl_xor(km, d);
            km = o > km ? o : km;
        }
        if (lane == 0) wtop[wv][it] = km;
        if (cur == km) {                       // keys unique (embed ~c)
            ++p;
            cur = (p == 1) ? k1 : (p == 2) ? k2 : (p == 3) ? k3 : (p == 4) ? k4
                : (p == 5) ? k5 : (p == 6) ? k6 : (p == 7) ? k7 : 0ull;
        }
    }
    __syncthreads();

    // parallel 4-way merge: desc A in lanes 0-31, reversed B in 32-63 ->
    // bitonic valley -> 6-stage half-cleaner, keep max if (lane&d)==0.
    if (wv < 2) {
        unsigned long long v = (lane < 32) ? wtop[2 * wv][lane]
                                           : wtop[2 * wv + 1][63 - lane];
        #pragma unroll
        for (int d = 32; d > 0; d >>= 1) {
            unsigned long long o = __shfl_xor(v, d);
            v = ((lane & d) == 0) ? (v > o ? v : o) : (v < o ? v : o);
        }
        if (lane < 32) m2[wv][lane] = v;
    }
    __syncthreads();
    if (wv == 0) {
        unsigned long long v = (lane < 32) ? m2[0][lane] : m2[1][63 - lane];
        #pragma unroll
        for (int d = 32; d > 0; d >>= 1) {
            unsigned long long o = __shfl_xor(v, d);
            v = ((lane & d) == 0) ? (v > o ? v : o) : (v < o ? v : o);
        }
        if (lane < 32) sel32[lane] = v;        // sorted desc, top-32 exact
    }
    __syncthreads();

    // exact f32 rescore of coarse top-32; 4 waves x 8 candidates
    float4 qv = ((const float4*)q)[(size_t)b * 64 + lane];
    float qsq = qv.x * qv.x + qv.y * qv.y + qv.z * qv.z + qv.w * qv.w;
    #pragma unroll
    for (int d = 1; d < 64; d <<= 1) qsq += __shfl_xor(qsq, d);
    float qi = 1.0f / fmaxf(sqrtf(qsq), EPS);

    for (int m = wv; m < 32; m += 4) {
        int idx = (int)(0xFFFFFFFFu - (unsigned)(sel32[m] & 0xFFFFFFFFull));
        float4 ev = ((const float4*)e)[(size_t)idx * 64 + lane];
        float dot = qv.x * ev.x + qv.y * ev.y + qv.z * ev.z + qv.w * ev.w;
        float ss  = ev.x * ev.x + ev.y * ev.y + ev.z * ev.z + ev.w * ev.w;
        #pragma unroll
        for (int d = 1; d < 64; d <<= 1) {
            dot += __shfl_xor(dot, d);
            ss  += __shfl_xor(ss, d);
        }
        if (lane == 0) {
            rs[m] = dot * qi * (1.0f / fmaxf(sqrtf(ss), EPS));
            ri[m] = idx;
        }
    }
    __syncthreads();

    if (t < 64) {       // top-8 of 32 (score desc, idx asc); keep rank j
        float val; int idx, slot;
        if (t < 32) { val = rs[t]; idx = ri[t]; slot = t; }
        else        { val = -INFINITY; idx = 0x7fffffff; slot = -1; }
        for (int pp = 0; pp < 8; ++pp) {
            float bs = val; int bi = idx, bsl = slot;
            #pragma unroll
            for (int d = 1; d < 64; d <<= 1) {
                float os = __shfl_xor(bs, d);
                int   oi = __shfl_xor(bi, d);
                int   osl = __shfl_xor(bsl, d);
                if (os > bs || (os == bs && oi < bi)) { bs = os; bi = oi; bsl = osl; }
            }
            if (t == 0 && pp == j) { out_scores[b * K_ + j] = bs; sel_c = bi; }
            if (slot == bsl) val = -INFINITY;
        }
    }
    __syncthreads();

    // gather this block's (b,j): 64KB read + 64KB write, nontemporal
    const int c = sel_c;
    const int m_ = *mode;
    const int flag = m_ ? (((const unsigned char*)icp)[c] != 0)
                        : (((const int*)icp)[c] != 0);
    f32x4* o4 = (f32x4*)out + ((size_t)b * K_ + j) * 4096;
    if (!flag) {
        const f32x4* s4 = (const f32x4*)epi + (size_t)c * 4096;
        #pragma unroll 4
        for (int i = t; i < 4096; i += 256)
            __builtin_nontemporal_store(__builtin_nontemporal_load(s4 + i), o4 + i);
    } else {
        const f32x4* s4 = (const f32x4*)comp + (size_t)c * 2048;
        #pragma unroll 4
        for (int i = t; i < 2048; i += 256)
            __builtin_nontemporal_store(__builtin_nontemporal_load(s4 + i), o4 + i);
        const f32x4 z = (f32x4){0.f, 0.f, 0.f, 0.f};
        #pragma unroll 4
        for (int i = 2048 + t; i < 4096; i += 256)
            __builtin_nontemporal_store(z, o4 + i);
    }
}

extern "C" void kernel_launch(void* const* d_in, const int* in_sizes, int n_in,
                              void* d_out, int out_size, void* d_ws, size_t ws_size,
                              hipStream_t stream) {
    const float* query = (const float*)d_in[0];
    const float* emb   = (const float*)d_in[1];
    const float* epi   = (const float*)d_in[2];
    const float* comp  = (const float*)d_in[3];
    const void*  icp   = d_in[4];
    float* out = (float*)d_out;

    unsigned long long* candbuf = (unsigned long long*)d_ws;          // 4 MB
    int* mode = (int*)((char*)d_ws + (4u << 20));
    float* out_scores = out + RET_;

    simsel_kernel<<<1025, 256, 0, stream>>>(query, emb, (const unsigned*)icp,
                                            candbuf, mode);
    merge_gather_kernel<<<B_ * K_, 256, 0, stream>>>(query, emb, candbuf, icp, mode,
                                                     epi, comp, out, out_scores);
}

// Round 14
// 102.961 us; speedup vs baseline: 1.1135x; 1.1135x over previous
//
#include <hip/hip_runtime.h>
#include <hip/hip_bf16.h>
#include <math.h>

#define B_  256
#define H_  256
#define C_  16384
#define S_  64
#define CS_ 32
#define K_  8
#define EPS 1e-8f
#define RET_ ((size_t)B_ * K_ * S_ * H_)   // 33,554,432 f32

typedef __attribute__((ext_vector_type(8))) short short8v;
typedef __attribute__((ext_vector_type(4))) float f32x4;

// ws: candbuf u64[256*2048] (4 MB) @0; mode i32 @4MB; topidx i32[2048] after.
// d_out: [retrieved 33.5M f32][top_scores 2048 f32]; no scratch in d_out.

__device__ inline unsigned short f2bf(float f) {   // native RTNE cvt (v_cvt_pk-able)
    return __builtin_bit_cast(unsigned short, __float2bfloat16(f));
}
__device__ inline unsigned ordf(float f) {         // order-preserving f32->u32
    unsigned u = __builtin_bit_cast(unsigned, f);
    return u ^ ((u >> 31) ? 0xFFFFFFFFu : 0x80000000u);
}
__device__ inline short8v pack8(float4 a, float4 b) {
    short8v r;
    r[0] = (short)f2bf(a.x); r[1] = (short)f2bf(a.y);
    r[2] = (short)f2bf(a.z); r[3] = (short)f2bf(a.w);
    r[4] = (short)f2bf(b.x); r[5] = (short)f2bf(b.y);
    r[6] = (short)f2bf(b.z); r[7] = (short)f2bf(b.w);
    return r;
}
__device__ inline void ce(unsigned long long& a, unsigned long long& b) {  // desc
    unsigned long long lo = a < b ? a : b;
    a = a < b ? b : a;
    b = lo;
}
// best: sorted desc. Merge with xor-partner's sorted-desc list -> top-8 of 16.
__device__ inline void merge_shfl(unsigned long long best[8], int xorlane) {
    unsigned long long m[8];
    #pragma unroll
    for (int i = 0; i < 8; ++i) {
        unsigned long long p = __shfl_xor(best[7 - i], xorlane);
        m[i] = best[i] > p ? best[i] : p;      // bitonic first step: top-8 set
    }
    ce(m[0], m[4]); ce(m[1], m[5]); ce(m[2], m[6]); ce(m[3], m[7]);
    ce(m[0], m[2]); ce(m[1], m[3]); ce(m[4], m[6]); ce(m[5], m[7]);
    ce(m[0], m[1]); ce(m[2], m[3]); ce(m[4], m[5]); ce(m[6], m[7]);
    #pragma unroll
    for (int i = 0; i < 8; ++i) best[i] = m[i];
}

// Fused bf16-MFMA sim + per-tile per-row top-8 (all-thread parallel).
// Block = 64b x 64c; K chunked by 32, LDS double-buffered staging: one
// barrier per phase, next-phase loads issued before the barrier.
// Block 1024: detect is_compressed storage width.
#define LSTR 40
__global__ __launch_bounds__(256) void simsel_kernel(const float* __restrict__ q,
                                                     const float* __restrict__ e,
                                                     const unsigned* __restrict__ icw,
                                                     unsigned long long* __restrict__ candbuf,
                                                     int* __restrict__ mode) {
    const int t = threadIdx.x;
    if (blockIdx.x == 1024) {   // byte-bool (1) vs int32 (0)
        __shared__ int f;
        if (t == 0) f = 0;
        __syncthreads();
        int any = 0;
        for (int i = t; i < 4096; i += 256)
            if (icw[i] & 0xFFFFFF00u) any = 1;
        if (any) atomicOr(&f, 1);
        __syncthreads();
        if (t == 0) *mode = f;
        return;
    }

    __shared__ union {
        unsigned short st[4][64 * LSTR];   // [Q0, Q1, E0, E1] 5.1 KB each
        float tile[64 * 65];               // f32 sim tile (16.6 KB)
    } sm;
    __shared__ float einv_s[64];
    const int lane = t & 63, wv = t >> 6;
    const int wm = wv >> 1, wn = wv & 1;
    // XCD swizzle: bids {x, x+8, x+16, x+24} share one c-tile on one XCD.
    const int bid = blockIdx.x;
    const int ct = (bid & 7) * 32 + (bid >> 5);
    const int bt = (bid >> 3) & 3;
    const int c0 = ct * 64, b0 = bt * 64;
    const int r = t >> 2, g = t & 3;              // staging: row, quarter
    const float4* q4 = (const float4*)q;
    const float4* e4 = (const float4*)e;

    float esq = 0.f;
    f32x4 acc[2][2];
    #pragma unroll
    for (int i = 0; i < 2; ++i)
        #pragma unroll
        for (int j = 0; j < 2; ++j) acc[i][j] = (f32x4){0.f, 0.f, 0.f, 0.f};

    // prologue: stage phase 0 into buffers 0
    {
        float4 qa0 = q4[(size_t)(b0 + r) * 64 + g * 2];
        float4 qa1 = q4[(size_t)(b0 + r) * 64 + g * 2 + 1];
        float4 ea0 = e4[(size_t)(c0 + r) * 64 + g * 2];
        float4 ea1 = e4[(size_t)(c0 + r) * 64 + g * 2 + 1];
        esq += ea0.x * ea0.x + ea0.y * ea0.y + ea0.z * ea0.z + ea0.w * ea0.w
             + ea1.x * ea1.x + ea1.y * ea1.y + ea1.z * ea1.z + ea1.w * ea1.w;
        *(short8v*)&sm.st[0][r * LSTR + g * 8] = pack8(qa0, qa1);
        *(short8v*)&sm.st[2][r * LSTR + g * 8] = pack8(ea0, ea1);
    }

    for (int hc = 0; hc < 8; ++hc) {
        const int cur = hc & 1, nxt = cur ^ 1;
        float4 qa0, qa1, ea0, ea1;
        if (hc < 7) {   // issue next-phase loads BEFORE the barrier
            qa0 = q4[(size_t)(b0 + r) * 64 + (hc + 1) * 8 + g * 2];
            qa1 = q4[(size_t)(b0 + r) * 64 + (hc + 1) * 8 + g * 2 + 1];
            ea0 = e4[(size_t)(c0 + r) * 64 + (hc + 1) * 8 + g * 2];
            ea1 = e4[(size_t)(c0 + r) * 64 + (hc + 1) * 8 + g * 2 + 1];
        }
        __syncthreads();   // buf[cur] staged & prior readers of buf[nxt] done

        short8v afr[2], bfr[2];
        #pragma unroll
        for (int mi = 0; mi < 2; ++mi)
            afr[mi] = *(short8v*)&sm.st[cur][(wm * 32 + mi * 16 + (lane & 15)) * LSTR + (lane >> 4) * 8];
        #pragma unroll
        for (int ni = 0; ni < 2; ++ni)
            bfr[ni] = *(short8v*)&sm.st[2 + cur][(wn * 32 + ni * 16 + (lane & 15)) * LSTR + (lane >> 4) * 8];
        #pragma unroll
        for (int mi = 0; mi < 2; ++mi)
            #pragma unroll
            for (int ni = 0; ni < 2; ++ni)
                acc[mi][ni] = __builtin_amdgcn_mfma_f32_16x16x32_bf16(
                    afr[mi], bfr[ni], acc[mi][ni], 0, 0, 0);

        if (hc < 7) {   // stage next phase into the other buffer
            esq += ea0.x * ea0.x + ea0.y * ea0.y + ea0.z * ea0.z + ea0.w * ea0.w
                 + ea1.x * ea1.x + ea1.y * ea1.y + ea1.z * ea1.z + ea1.w * ea1.w;
            *(short8v*)&sm.st[nxt][r * LSTR + g * 8] = pack8(qa0, qa1);
            *(short8v*)&sm.st[2 + nxt][r * LSTR + g * 8] = pack8(ea0, ea1);
        }
    }

    esq += __shfl_xor(esq, 1);
    esq += __shfl_xor(esq, 2);                    // 4-lane group = one e row
    if (g == 0) einv_s[r] = 1.0f / fmaxf(sqrtf(esq), EPS);
    __syncthreads();   // drains final phase's LDS reads; tile may now alias

    // dump scaled sims over the staging region
    #pragma unroll
    for (int mi = 0; mi < 2; ++mi)
        #pragma unroll
        for (int j = 0; j < 4; ++j) {
            int row = wm * 32 + mi * 16 + (lane >> 4) * 4 + j;
            #pragma unroll
            for (int ni = 0; ni < 2; ++ni) {
                int col = wn * 32 + ni * 16 + (lane & 15);
                sm.tile[row * 65 + col] = acc[mi][ni][j] * einv_s[col];
            }
        }
    __syncthreads();

    // thread (r,g): top-8 of its 16 cols, then 2 shfl-merge rounds -> top-8 of 64
    unsigned long long best[8];
    #pragma unroll
    for (int k = 0; k < 8; ++k) best[k] = 0ull;
    for (int i = 0; i < 16; ++i) {
        int c = g * 16 + i;
        float v = sm.tile[r * 65 + c];
        unsigned long long key = ((unsigned long long)ordf(v) << 32)
                               | (unsigned)(0xFFFFFFFFu - (unsigned)(c0 + c));
        if (key > best[7]) {
            best[7] = key;
            #pragma unroll
            for (int k = 7; k > 0; --k)
                if (best[k] > best[k - 1]) {
                    unsigned long long tmp = best[k];
                    best[k] = best[k - 1]; best[k - 1] = tmp;
                }
        }
    }
    merge_shfl(best, 1);   // quarters 0<->1, 2<->3
    merge_shfl(best, 2);   // -> exact per-row top-8 (all 4 threads agree)
    if (g == 0) {
        #pragma unroll
        for (int k = 0; k < 8; ++k)
            candbuf[(size_t)(b0 + r) * 2048 + ct * 8 + k] = best[k];
    }
}

// One block per row b. candbuf row = 256 sorted-desc 8-lists. K-way pop-merge
// per wave -> 4 sorted-32 lists -> parallel cross-lane bitonic 4-way merge ->
// exact coarse top-32 -> f32 rescore -> final top-8 (JAX tie-break).
__global__ __launch_bounds__(256) void merge_kernel(const float* __restrict__ q,
                                                    const float* __restrict__ e,
                                                    const unsigned long long* __restrict__ candbuf,
                                                    float* __restrict__ out_scores,
                                                    int* __restrict__ top_idx) {
    __shared__ unsigned long long wtop[4][32];
    __shared__ unsigned long long m2[2][32];
    __shared__ unsigned long long sel32[32];
    __shared__ float rs[32];
    __shared__ int   ri[32];
    const int t = threadIdx.x, b = blockIdx.x;
    const int wv = t >> 6, lane = t & 63;

    // lane's tile list (sorted desc), kept in registers (static select-chain)
    const unsigned long long* lp = candbuf + (size_t)b * 2048 + (size_t)(wv * 64 + lane) * 8;
    unsigned long long k0 = lp[0], k1 = lp[1], k2 = lp[2], k3 = lp[3],
                       k4 = lp[4], k5 = lp[5], k6 = lp[6], k7 = lp[7];
    int p = 0;
    unsigned long long cur = k0;

    for (int it = 0; it < 32; ++it) {          // pop 32: exact wave top-32
        unsigned long long km = cur;
        #pragma unroll
        for (int d = 1; d < 64; d <<= 1) {
            unsigned long long o = __shfl_xor(km, d);
            km = o > km ? o : km;
        }
        if (lane == 0) wtop[wv][it] = km;
        if (cur == km) {                       // keys unique (embed ~c)
            ++p;
            cur = (p == 1) ? k1 : (p == 2) ? k2 : (p == 3) ? k3 : (p == 4) ? k4
                : (p == 5) ? k5 : (p == 6) ? k6 : (p == 7) ? k7 : 0ull;
        }
    }
    __syncthreads();

    // parallel 4-way merge: desc A in lanes 0-31, reversed B in 32-63 ->
    // bitonic valley -> 6-stage half-cleaner, keep max if (lane&d)==0.
    if (wv < 2) {
        unsigned long long v = (lane < 32) ? wtop[2 * wv][lane]
                                           : wtop[2 * wv + 1][63 - lane];
        #pragma unroll
        for (int d = 32; d > 0; d >>= 1) {
            unsigned long long o = __shfl_xor(v, d);
            v = ((lane & d) == 0) ? (v > o ? v : o) : (v < o ? v : o);
        }
        if (lane < 32) m2[wv][lane] = v;
    }
    __syncthreads();
    if (wv == 0) {
        unsigned long long v = (lane < 32) ? m2[0][lane] : m2[1][63 - lane];
        #pragma unroll
        for (int d = 32; d > 0; d >>= 1) {
            unsigned long long o = __shfl_xor(v, d);
            v = ((lane & d) == 0) ? (v > o ? v : o) : (v < o ? v : o);
        }
        if (lane < 32) sel32[lane] = v;        // sorted desc, top-32 exact
    }
    __syncthreads();

    // exact f32 rescore of coarse top-32; 4 waves x 8 candidates
    float4 qv = ((const float4*)q)[(size_t)b * 64 + lane];
    float qsq = qv.x * qv.x + qv.y * qv.y + qv.z * qv.z + qv.w * qv.w;
    #pragma unroll
    for (int d = 1; d < 64; d <<= 1) qsq += __shfl_xor(qsq, d);
    float qi = 1.0f / fmaxf(sqrtf(qsq), EPS);

    for (int m = wv; m < 32; m += 4) {
        int idx = (int)(0xFFFFFFFFu - (unsigned)(sel32[m] & 0xFFFFFFFFull));
        float4 ev = ((const float4*)e)[(size_t)idx * 64 + lane];
        float dot = qv.x * ev.x + qv.y * ev.y + qv.z * ev.z + qv.w * ev.w;
        float ss  = ev.x * ev.x + ev.y * ev.y + ev.z * ev.z + ev.w * ev.w;
        #pragma unroll
        for (int d = 1; d < 64; d <<= 1) {
            dot += __shfl_xor(dot, d);
            ss  += __shfl_xor(ss, d);
        }
        if (lane == 0) {
            rs[m] = dot * qi * (1.0f / fmaxf(sqrtf(ss), EPS));
            ri[m] = idx;
        }
    }
    __syncthreads();

    if (t < 64) {       // final top-8 of 32 (score desc, idx asc)
        float val; int idx, slot;
        if (t < 32) { val = rs[t]; idx = ri[t]; slot = t; }
        else        { val = -INFINITY; idx = 0x7fffffff; slot = -1; }
        for (int pp = 0; pp < 8; ++pp) {
            float bs = val; int bi = idx, bsl = slot;
            #pragma unroll
            for (int d = 1; d < 64; d <<= 1) {
                float os = __shfl_xor(bs, d);
                int   oi = __shfl_xor(bi, d);
                int   osl = __shfl_xor(bsl, d);
                if (os > bs || (os == bs && oi < bi)) { bs = os; bi = oi; bsl = osl; }
            }
            if (t == 0) { out_scores[b * K_ + pp] = bs; top_idx[b * K_ + pp] = bi; }
            if (slot == bsl) val = -INFINITY;
        }
    }
}

// One block per (b,j): contiguous 64KB read + 64KB write, nontemporal.
__global__ __launch_bounds__(256) void gather_kernel(const float* __restrict__ epi,
                                                     const float* __restrict__ comp,
                                                     const void* __restrict__ icp,
                                                     const int* __restrict__ top_idx,
                                                     const int* __restrict__ mode,
                                                     float* __restrict__ out) {
    const int bj = blockIdx.x;
    const int c = top_idx[bj];
    const int m = *mode;
    const int flag = m ? (((const unsigned char*)icp)[c] != 0)
                       : (((const int*)icp)[c] != 0);
    const int t = threadIdx.x;
    f32x4* o4 = (f32x4*)out + (size_t)bj * 4096;
    if (!flag) {
        const f32x4* s4 = (const f32x4*)epi + (size_t)c * 4096;
        #pragma unroll 4
        for (int i = t; i < 4096; i += 256)
            __builtin_nontemporal_store(__builtin_nontemporal_load(s4 + i), o4 + i);
    } else {
        const f32x4* s4 = (const f32x4*)comp + (size_t)c * 2048;
        #pragma unroll 4
        for (int i = t; i < 2048; i += 256)
            __builtin_nontemporal_store(__builtin_nontemporal_load(s4 + i), o4 + i);
        const f32x4 z = (f32x4){0.f, 0.f, 0.f, 0.f};
        #pragma unroll 4
        for (int i = 2048 + t; i < 4096; i += 256)
            __builtin_nontemporal_store(z, o4 + i);
    }
}

extern "C" void kernel_launch(void* const* d_in, const int* in_sizes, int n_in,
                              void* d_out, int out_size, void* d_ws, size_t ws_size,
                              hipStream_t stream) {
    const float* query = (const float*)d_in[0];
    const float* emb   = (const float*)d_in[1];
    const float* epi   = (const float*)d_in[2];
    const float* comp  = (const float*)d_in[3];
    const void*  icp   = d_in[4];
    float* out = (float*)d_out;

    unsigned long long* candbuf = (unsigned long long*)d_ws;          // 4 MB
    int* mode   = (int*)((char*)d_ws + (4u << 20));
    int* topidx = mode + 1;
    float* out_scores = out + RET_;

    simsel_kernel<<<1025, 256, 0, stream>>>(query, emb, (const unsigned*)icp,
                                            candbuf, mode);
    merge_kernel<<<B_, 256, 0, stream>>>(query, emb, candbuf, out_scores, topidx);
    gather_kernel<<<B_ * K_, 256, 0, stream>>>(epi, comp, icp, topidx, mode, out);
}